// Round 11
// baseline (128.766 us; speedup 1.0000x reference)
//
#include <hip/hip_runtime.h>
#include <hip/hip_bf16.h>
#include <stdint.h>

// Problem constants
#define LL   4096
#define CCH  64
#define DOUT 512
#define MM   8192            // B*NP patch-rows
#define TT   0.001f          // 1/FS

using bf16 = __hip_bfloat16;
typedef __attribute__((ext_vector_type(8))) short bf16x8;
typedef __attribute__((ext_vector_type(4))) float f32x4;

#define MFMA(a, b, c) __builtin_amdgcn_mfma_f32_16x16x32_bf16((a), (b), (c), 0, 0, 0)

// Async global->LDS. NOTE: global address is PER-LANE (lane i fetches its own
// 16B); LDS dest is wave-uniform base + lane*16. Caller passes lane-offset g.
__device__ __forceinline__ void async_copy16(void* lds, const void* g) {
    __builtin_amdgcn_global_load_lds(
        (const __attribute__((address_space(1))) void*)g,
        (__attribute__((address_space(3))) void*)lds,
        16, 0, 0);
}

__device__ __forceinline__ uint2 pack4_bf16(float a, float b, float c, float d) {
    union { bf16 h[4]; uint2 u; } p;
    p.h[0] = __float2bfloat16(a);
    p.h[1] = __float2bfloat16(b);
    p.h[2] = __float2bfloat16(c);
    p.h[3] = __float2bfloat16(d);
    return p.u;
}

// ---------------------------------------------------------------------------
// prep: repack weights into k-chunked layout (chunk ic = 32 consecutive k per
// col, contiguous): w1g[(ic*512+col)*32+kk] = w1[col][l*32+j], k=ic*32+kk,
// l=k>>4, j=k&15 (x-columns only). w2g likewise from w2. Plus affine terms.
// ---------------------------------------------------------------------------
__global__ __launch_bounds__(256) void prep(
    const float* __restrict__ w1, const float* __restrict__ b1,
    const float* __restrict__ w2,
    bf16* __restrict__ w1g, bf16* __restrict__ w2g,
    float* __restrict__ A1, float* __restrict__ C1)
{
    const int blk = blockIdx.x;
    if (blk < 512) {
        int g   = blk * 256 + threadIdx.x;          // 0..131071, 4 elems each
        int kk0 = (g & 7) * 4;                      // 0,4,..,28
        int col = (g >> 3) & 511;
        int ic  = g >> 12;                          // 0..31
        int l   = ic * 2 + (kk0 >> 4);
        int j0  = kk0 & 15;
        float4 v = *(const float4*)(w1 + (size_t)col * 2048 + l * 32 + j0);
        *(uint2*)(w1g + ((size_t)(ic * 512 + col) * 32 + kk0)) =
            pack4_bf16(v.x, v.y, v.z, v.w);
    } else if (blk < 768) {
        int g   = (blk - 512) * 256 + threadIdx.x;  // 0..65535
        int kk0 = (g & 7) * 4;
        int col = (g >> 3) & 511;
        int ic2 = g >> 12;                          // 0..15
        float4 v = *(const float4*)(w2 + (size_t)col * 512 + ic2 * 32 + kk0);
        *(uint2*)(w2g + ((size_t)(ic2 * 512 + col) * 32 + kk0)) =
            pack4_bf16(v.x, v.y, v.z, v.w);
    } else {
        const int o = (blk - 768) * 4 + (threadIdx.x >> 6);
        const int l = threadIdx.x & 63;
        const float* wr = w1 + (size_t)o * 2048 + l * 32 + 16;
        float s0 = 0.f;
#pragma unroll
        for (int j = 0; j < 16; ++j) s0 += wr[j];
        float s1 = (float)l * s0;
#pragma unroll
        for (int off = 32; off > 0; off >>= 1) {
            s0 += __shfl_down(s0, off);
            s1 += __shfl_down(s1, off);
        }
        if (l == 0) {
            A1[o] = TT * s0;
            C1[o] = b1[o] + TT * s1;
        }
    }
}

// ---------------------------------------------------------------------------
// gather: feats_g[(ic*MM+m)*32+kk] = bf16(x[b, sL[m]+2ic+(kk>>4), sC[m]+(kk&15)])
// One thread per (ic, m): reads 2x64B from x, writes one contiguous 64B chunk.
// m is the fast index -> writes fully coalesced.
// ---------------------------------------------------------------------------
__global__ __launch_bounds__(256) void gather(
    const float* __restrict__ x, const int* __restrict__ sL,
    const int* __restrict__ sC, bf16* __restrict__ fg)
{
    const int g  = blockIdx.x * 256 + threadIdx.x;   // 0..262143
    const int ic = g >> 13;                          // 0..31
    const int m  = g & 8191;
    const int b  = m >> 8;
    const int sl = sL[m];
    const int sc = sC[m];
    const float* p = x + ((size_t)b * LL + sl + ic * 2) * CCH + sc;
    float4 v0 = *(const float4*)(p);
    float4 v1 = *(const float4*)(p + 4);
    float4 v2 = *(const float4*)(p + 8);
    float4 v3 = *(const float4*)(p + 12);
    float4 u0 = *(const float4*)(p + CCH);
    float4 u1 = *(const float4*)(p + CCH + 4);
    float4 u2 = *(const float4*)(p + CCH + 8);
    float4 u3 = *(const float4*)(p + CCH + 12);
    bf16* dst = fg + ((size_t)ic * MM + m) * 32;
    uint4 o;
    uint2 a, c;
    a = pack4_bf16(v0.x, v0.y, v0.z, v0.w);
    c = pack4_bf16(v1.x, v1.y, v1.z, v1.w);
    o.x = a.x; o.y = a.y; o.z = c.x; o.w = c.y;  *(uint4*)(dst)      = o;
    a = pack4_bf16(v2.x, v2.y, v2.z, v2.w);
    c = pack4_bf16(v3.x, v3.y, v3.z, v3.w);
    o.x = a.x; o.y = a.y; o.z = c.x; o.w = c.y;  *(uint4*)(dst + 8)  = o;
    a = pack4_bf16(u0.x, u0.y, u0.z, u0.w);
    c = pack4_bf16(u1.x, u1.y, u1.z, u1.w);
    o.x = a.x; o.y = a.y; o.z = c.x; o.w = c.y;  *(uint4*)(dst + 16) = o;
    a = pack4_bf16(u2.x, u2.y, u2.z, u2.w);
    c = pack4_bf16(u3.x, u3.y, u3.z, u3.w);
    o.x = a.x; o.y = a.y; o.z = c.x; o.w = c.y;  *(uint4*)(dst + 24) = o;
}

// ---------------------------------------------------------------------------
// GEMM1 inverted: weights STATIONARY in LDS, activations streamed.
// Block = 256 rows x 64 cols (grid 32x8). w1 N-slice (64 cols x 1024 k =
// 128 KB) loaded once via global_load_lds (per-lane global addresses!);
// K-loop has NO barriers (LDS is read-only). A-frags are contiguous 1 KB
// wave-reads from feats_g. Epilogue: silu(acc + sL*A1 + C1) -> h_g.
// ---------------------------------------------------------------------------
__global__ __launch_bounds__(512, 2) void gemm1_inv(
    const bf16* __restrict__ fg, const bf16* __restrict__ w1g,
    const float* __restrict__ A1, const float* __restrict__ C1,
    const int* __restrict__ sLg, bf16* __restrict__ hg)
{
    __shared__ __align__(16) bf16 Bs[32 * 64 * 32];   // 128 KB
    const int t    = threadIdx.x;
    const int lane = t & 63;
    const int wave = t >> 6;          // 0..7 -> rows [r0+wave*32, +32)
    const int fr   = lane & 15;
    const int fq   = lane >> 4;
    const int r0   = blockIdx.x * 256;
    const int n0   = blockIdx.y * 64;

    // One-time LDS fill: wave w stages ic in {w, w+8, w+16, w+24}, 4x1KB each.
    // Global side carries the per-lane offset (lane*8 bf16 = lane*16 B).
    const bf16* const w1s = w1g + (size_t)lane * 8;
#pragma unroll
    for (int s = 0; s < 4; ++s) {
        const int ic = wave + s * 8;
#pragma unroll
        for (int q = 0; q < 4; ++q)
            async_copy16(&Bs[(ic * 64 + q * 16) * 32],
                         w1s + ((size_t)ic * 512 + n0 + q * 16) * 32);
    }

    // A-frag base: lane covers row fr (of 16), k fq*8..+8 within a chunk
    const bf16* ab = fg + ((size_t)(r0 + wave * 32 + fr)) * 32 + fq * 8;
    bf16x8 aA[2], aB[2];
    aA[0] = *(const bf16x8*)(ab);
    aA[1] = *(const bf16x8*)(ab + 16 * 32);
    aB[0] = *(const bf16x8*)(ab + (size_t)MM * 32);
    aB[1] = *(const bf16x8*)(ab + (size_t)MM * 32 + 16 * 32);
    __syncthreads();                  // Bs DMA drained (vmcnt0), tile ready

    f32x4 acc[2][4] = {};
#pragma unroll
    for (int it = 0; it < 16; ++it) {
        {   // chunk ic = 2it (aA), then reload aA <- 2it+2
            const int ic = 2 * it;
            bf16x8 bfrg[4];
#pragma unroll
            for (int j = 0; j < 4; ++j)
                bfrg[j] = *(const bf16x8*)&Bs[(ic * 64 + j * 16 + fr) * 32 + fq * 8];
#pragma unroll
            for (int j = 0; j < 4; ++j) {
                acc[0][j] = MFMA(aA[0], bfrg[j], acc[0][j]);
                acc[1][j] = MFMA(aA[1], bfrg[j], acc[1][j]);
            }
            if (it < 15) {
                const bf16* p = ab + (size_t)(ic + 2) * MM * 32;
                aA[0] = *(const bf16x8*)(p);
                aA[1] = *(const bf16x8*)(p + 16 * 32);
            }
        }
        {   // chunk ic = 2it+1 (aB), then reload aB <- 2it+3
            const int ic = 2 * it + 1;
            bf16x8 bfrg[4];
#pragma unroll
            for (int j = 0; j < 4; ++j)
                bfrg[j] = *(const bf16x8*)&Bs[(ic * 64 + j * 16 + fr) * 32 + fq * 8];
#pragma unroll
            for (int j = 0; j < 4; ++j) {
                acc[0][j] = MFMA(aB[0], bfrg[j], acc[0][j]);
                acc[1][j] = MFMA(aB[1], bfrg[j], acc[1][j]);
            }
            if (it < 15) {
                const bf16* p = ab + (size_t)(ic + 2) * MM * 32;
                aB[0] = *(const bf16x8*)(p);
                aB[1] = *(const bf16x8*)(p + 16 * 32);
            }
        }
    }

    // Epilogue: silu(acc + sL*A1 + C1) -> h_g[(icg*MM+row)*32 + kc]
    float slr[2][4];
#pragma unroll
    for (int i = 0; i < 2; ++i)
#pragma unroll
        for (int rr = 0; rr < 4; ++rr)
            slr[i][rr] = (float)sLg[r0 + wave * 32 + i * 16 + fq * 4 + rr];
#pragma unroll
    for (int j = 0; j < 4; ++j) {
        const int col = n0 + j * 16 + fr;
        const float av = A1[col];
        const float cv = C1[col];
        const int icg = (n0 >> 5) + (j >> 1);
        const int kc  = (j & 1) * 16 + fr;
#pragma unroll
        for (int i = 0; i < 2; ++i)
#pragma unroll
            for (int rr = 0; rr < 4; ++rr) {
                const int row = r0 + wave * 32 + i * 16 + fq * 4 + rr;
                float v = acc[i][j][rr] + slr[i][rr] * av + cv;
                v = v / (1.0f + __expf(-v));
                hg[((size_t)icg * MM + row) * 32 + kc] = __float2bfloat16(v);
            }
    }
}

// ---------------------------------------------------------------------------
// GEMM2 inverted: w2 N-slice (64 cols x 512 k = 64 KB) stationary in LDS,
// h_g streamed. Block = 128 rows x 64 cols (grid 64x8), 2 blocks/CU.
// ---------------------------------------------------------------------------
__global__ __launch_bounds__(512, 4) void gemm2_inv(
    const bf16* __restrict__ hg, const bf16* __restrict__ w2g,
    const float* __restrict__ b2, float* __restrict__ out)
{
    __shared__ __align__(16) bf16 Bs[16 * 64 * 32];   // 64 KB
    const int t    = threadIdx.x;
    const int lane = t & 63;
    const int wave = t >> 6;          // 0..7 -> rows [r0+wave*16, +16)
    const int fr   = lane & 15;
    const int fq   = lane >> 4;
    const int r0   = blockIdx.x * 128;
    const int n0   = blockIdx.y * 64;

    const bf16* const w2s = w2g + (size_t)lane * 8;   // per-lane global offset
#pragma unroll
    for (int s = 0; s < 2; ++s) {
        const int ic = wave + s * 8;
#pragma unroll
        for (int q = 0; q < 4; ++q)
            async_copy16(&Bs[(ic * 64 + q * 16) * 32],
                         w2s + ((size_t)ic * 512 + n0 + q * 16) * 32);
    }

    const bf16* ab = hg + ((size_t)(r0 + wave * 16 + fr)) * 32 + fq * 8;
    bf16x8 aA = *(const bf16x8*)(ab);
    bf16x8 aB = *(const bf16x8*)(ab + (size_t)MM * 32);
    __syncthreads();

    f32x4 acc[4] = {};
#pragma unroll
    for (int it = 0; it < 8; ++it) {
        {
            const int ic = 2 * it;
            bf16x8 bfrg[4];
#pragma unroll
            for (int j = 0; j < 4; ++j)
                bfrg[j] = *(const bf16x8*)&Bs[(ic * 64 + j * 16 + fr) * 32 + fq * 8];
#pragma unroll
            for (int j = 0; j < 4; ++j)
                acc[j] = MFMA(aA, bfrg[j], acc[j]);
            if (it < 7)
                aA = *(const bf16x8*)(ab + (size_t)(ic + 2) * MM * 32);
        }
        {
            const int ic = 2 * it + 1;
            bf16x8 bfrg[4];
#pragma unroll
            for (int j = 0; j < 4; ++j)
                bfrg[j] = *(const bf16x8*)&Bs[(ic * 64 + j * 16 + fr) * 32 + fq * 8];
#pragma unroll
            for (int j = 0; j < 4; ++j)
                acc[j] = MFMA(aB, bfrg[j], acc[j]);
            if (it < 7)
                aB = *(const bf16x8*)(ab + (size_t)(ic + 2) * MM * 32);
        }
    }

#pragma unroll
    for (int j = 0; j < 4; ++j) {
        const int col = n0 + j * 16 + fr;
        const float bv = b2[col];
#pragma unroll
        for (int rr = 0; rr < 4; ++rr) {
            const int row = r0 + wave * 16 + fq * 4 + rr;
            __builtin_nontemporal_store(acc[j][rr] + bv,
                                        out + (size_t)row * 512 + col);
        }
    }
}

// ---------------------------------------------------------------------------
extern "C" void kernel_launch(void* const* d_in, const int* in_sizes, int n_in,
                              void* d_out, int out_size, void* d_ws, size_t ws_size,
                              hipStream_t stream)
{
    const float* x  = (const float*)d_in[0];
    const int*   sL = (const int*)  d_in[1];
    const int*   sC = (const int*)  d_in[2];
    const float* w1 = (const float*)d_in[3];
    const float* b1 = (const float*)d_in[4];
    const float* w2 = (const float*)d_in[5];
    const float* b2 = (const float*)d_in[6];
    float* out = (float*)d_out;

    char* ws = (char*)d_ws;
    bf16*  w1g = (bf16*)ws;                          // 1 MB
    bf16*  w2g = (bf16*)(ws + (1 << 20));            // 0.5 MB
    float* A1  = (float*)(ws + (1 << 20) + (1 << 19));
    float* C1  = A1 + DOUT;
    bf16*  fg  = (bf16*)(ws + (2 << 20));            // feats_g: 16 MB
    bf16*  hg  = (bf16*)(ws + (2 << 20) + ((size_t)MM * 1024 * 2));  // h_g: 8 MB

    prep<<<896, 256, 0, stream>>>(w1, b1, w2, w1g, w2g, A1, C1);
    gather<<<1024, 256, 0, stream>>>(x, sL, sC, fg);
    gemm1_inv<<<dim3(32, 8), 512, 0, stream>>>(fg, w1g, A1, C1, sL, hg);
    gemm2_inv<<<dim3(64, 8), 512, 0, stream>>>(hg, w2g, b2, out);
}